// Round 13
// baseline (118.345 us; speedup 1.0000x reference)
//
#include <hip/hip_runtime.h>
#include <stdint.h>

typedef __attribute__((ext_vector_type(8))) _Float16 half8;
typedef __attribute__((ext_vector_type(2))) __fp16 fp16x2;
typedef __attribute__((ext_vector_type(16))) float floatx16;
typedef __attribute__((ext_vector_type(2))) short s16x2;
typedef unsigned int u32;
typedef unsigned short u16;

// f32 pair -> packed f16 (a->low16, b->high16). Builtin returns __fp16-vector.
// NOTE R7: v_cvt_pk_bf16_f32 asm returns garbage on gfx950. NOTE R8: inline-asm
// v_mfma corrupts results (no hazard handling) — intrinsics only.
__device__ __forceinline__ u32 pkf16(float a, float b) {
  union { fp16x2 v; u32 u; } c;
  c.v = __builtin_amdgcn_cvt_pkrtz(a, b);
  return c.u;
}

// relu on packed f16 pair: signed-i16 max with 0. R5/R10-proven.
__device__ __forceinline__ u32 relu_pk(u32 t) {
  union { u32 u; s16x2 v; } c;
  c.u = t;
  s16x2 zz = {0, 0};
  c.v = __builtin_elementwise_max(c.v, zz);  // v_pk_max_i16
  return c.u;
}

__device__ __forceinline__ u16 rtnh(float a) {
  union { _Float16 h; u16 u; } c;
  c.h = (_Float16)a;
  return c.u;
}

__device__ __forceinline__ fp16x2 as_h2(u32 x) {
  union { u32 u; fp16x2 h; } c;
  c.u = x;
  return c.h;
}

// channel<->k-slot permutation (involution): swap bits 2,3 of low nibble.
__device__ __forceinline__ int sigperm(int k) {
  int r = k & 15;
  int s = (r & 3) | ((r & 4) << 1) | ((r & 8) >> 1);
  return (k & ~15) | s;
}

__device__ __forceinline__ half8 packhalf(const floatx16 a, int base, bool relu) {
  union { u32 u[4]; half8 v; } r;
#pragma unroll
  for (int i = 0; i < 4; ++i) {
    u32 t = pkf16(a[base + 2 * i], a[base + 2 * i + 1]);
    r.u[i] = relu ? relu_pk(t) : t;
  }
  return r.v;
}

#define MFMA(A, B, C) __builtin_amdgcn_mfma_f32_32x32x16_f16(A, B, C, 0, 0, 0)

// Frag pool (frag = 64 lanes x 16B):
//  0..1  s0[rt]        2..9  s1[rt*4+ks]    10..17 Wf[rt*4+ks] (= cw0[:,3:18]@sw2[1:,:])
// 18..19 Wv[rt] (views)  20..27 c1   28..35 c2   36..39 c3[ks]
// 40..43 wsig[q]: per-lane sigma-dot weights matching b{q} channel order
#define NFRAG 44

__global__ void build_pool(
    const float* __restrict__ w_s0, const float* __restrict__ w_s1,
    const float* __restrict__ w_s2, const float* __restrict__ w_c0,
    const float* __restrict__ w_c1, const float* __restrict__ w_c2,
    const float* __restrict__ w_c3, uint4* __restrict__ pool) {
  const int f = blockIdx.x;
  const int lane = threadIdx.x;      // 0..63
  const int m = lane & 31;
  const int hi = lane >> 5;
  const int kb = hi << 3;

  union { u16 e[8]; uint4 q; } u;
  if (f < 2) {                         // s0: 64x3, K padded to 16
    const int row = f * 32 + m;
#pragma unroll
    for (int j = 0; j < 8; ++j) {
      const int k = kb + j;
      u.e[j] = (k < 3) ? rtnh(w_s0[row * 3 + k]) : (u16)0;
    }
  } else if (f < 10) {                 // s1: 64x64
    const int g = f - 2, rt = g >> 2, ks = g & 3;
    const int row = rt * 32 + m;
#pragma unroll
    for (int j = 0; j < 8; ++j)
      u.e[j] = rtnh(w_s1[row * 64 + sigperm(ks * 16 + kb + j)]);
  } else if (f < 18) {                 // Wf = cw0[:,3:18] @ sw2[1:16,:], 64x64
    const int g = f - 10, rt = g >> 2, ks = g & 3;
    const int row = rt * 32 + m;
#pragma unroll
    for (int j = 0; j < 8; ++j) {
      const int col = sigperm(ks * 16 + kb + j);
      float acc = 0.f;
      for (int g2 = 0; g2 < 15; ++g2)
        acc += w_c0[row * 18 + 3 + g2] * w_s2[(1 + g2) * 64 + col];
      u.e[j] = rtnh(acc);
    }
  } else if (f < 20) {                 // Wv: views, K=16 with slots 0..2 used
    const int rt = f - 18;
    const int row = rt * 32 + m;
#pragma unroll
    for (int j = 0; j < 8; ++j) {
      const int kk = kb + j;
      u16 v = rtnh(w_c0[row * 18 + ((kk < 3) ? kk : 0)]);
      u.e[j] = (kk < 3) ? v : (u16)0;
    }
  } else if (f < 28) {                 // c1: 64x64
    const int g = f - 20, rt = g >> 2, ks = g & 3;
    const int row = rt * 32 + m;
#pragma unroll
    for (int j = 0; j < 8; ++j)
      u.e[j] = rtnh(w_c1[row * 64 + sigperm(ks * 16 + kb + j)]);
  } else if (f < 36) {                 // c2: 64x64
    const int g = f - 28, rt = g >> 2, ks = g & 3;
    const int row = rt * 32 + m;
#pragma unroll
    for (int j = 0; j < 8; ++j)
      u.e[j] = rtnh(w_c2[row * 64 + sigperm(ks * 16 + kb + j)]);
  } else if (f < 40) {                 // c3: 3x64 (rows 3..31 zero)
    const int ks = f - 36;
    const int row = (m < 3) ? m : 0;
#pragma unroll
    for (int j = 0; j < 8; ++j) {
      u16 v = rtnh(w_c3[row * 64 + sigperm(ks * 16 + kb + j)]);
      u.e[j] = (m < 3) ? v : (u16)0;
    }
  } else {                             // wsig[q]: sw2 row 0 in b{q} lane order
    const int q = f - 40;
#pragma unroll
    for (int j = 0; j < 8; ++j) {
      const int c = 16 * q + (j & 3) + 8 * (j >> 2) + 4 * hi;
      u.e[j] = rtnh(w_s2[c]);          // row 0 of sw2 (16x64)
    }
  }
  pool[f * 64 + lane] = u.q;
}

// 3-tile ILP: live set ~200 unified regs (acc 96 + b-frags 48 + misc).
// (256,2) caps at 256 — fits. (512,7) spilled catastrophically in R6.
__global__ __launch_bounds__(256, 2) void nerf_fused(
    const float* __restrict__ x, const uint4* __restrict__ pool,
    float* __restrict__ out, int npts) {
  __shared__ __align__(16) u16 wl[NFRAG * 512];  // 45056 B

  {
    uint4* lp = (uint4*)wl;
    for (int i = threadIdx.x; i < NFRAG * 64; i += 256) lp[i] = pool[i];
  }
  __syncthreads();

  const int lane = threadIdx.x & 63;
  const int wid = threadIdx.x >> 6;
  const int m = lane & 31;
  const int hi = lane >> 5;

#define LD(F) (*(const half8*)(wl + (F) * 512 + lane * 8))

  const int ntiles = npts >> 5;
  const int wgid = blockIdx.x * 4 + wid;
  const floatx16 z = (floatx16)0.0f;

  // ---- 3 tiles per wave, single pass (no loop) ----
  int pt[3];
  bool ok[3];
#pragma unroll
  for (int i = 0; i < 3; ++i) {
    int tl = wgid * 3 + i;
    ok[i] = tl < ntiles;
    if (tl > ntiles - 1) tl = ntiles - 1;
    pt[i] = (tl << 5) | m;
  }

  union { u32 u[4]; half8 v; } bx[3], bv[3];
#pragma unroll
  for (int i = 0; i < 3; ++i) {
    const float2* xp = (const float2*)(x + (size_t)pt[i] * 6);
    const float2 f0 = xp[0], f1 = xp[1], f2 = xp[2];
    bx[i].u[0] = hi ? 0u : pkf16(f0.x, f0.y);
    bx[i].u[1] = hi ? 0u : pkf16(f1.x, 0.0f);
    bx[i].u[2] = 0u; bx[i].u[3] = 0u;
    bv[i].u[0] = hi ? 0u : pkf16(f1.y, f2.x);
    bv[i].u[1] = hi ? 0u : pkf16(f2.y, 0.0f);
    bv[i].u[2] = 0u; bv[i].u[3] = 0u;
  }

  floatx16 h0[3], h1[3];
  half8 b0[3], b1[3], b2[3], b3[3];
  half8 w;

  // sigma L0 (K=3 padded)
  w = LD(0);
#pragma unroll
  for (int i = 0; i < 3; ++i) h0[i] = MFMA(w, bx[i].v, z);
  w = LD(1);
#pragma unroll
  for (int i = 0; i < 3; ++i) h1[i] = MFMA(w, bx[i].v, z);
#pragma unroll
  for (int i = 0; i < 3; ++i) {
    b0[i] = packhalf(h0[i], 0, true); b1[i] = packhalf(h0[i], 8, true);
    b2[i] = packhalf(h1[i], 0, true); b3[i] = packhalf(h1[i], 8, true);
  }

  // sigma L1 (64->64) -> h2
  w = LD(2);
#pragma unroll
  for (int i = 0; i < 3; ++i) h0[i] = MFMA(w, b0[i], z);
  w = LD(6);
#pragma unroll
  for (int i = 0; i < 3; ++i) h1[i] = MFMA(w, b0[i], z);
  w = LD(3);
#pragma unroll
  for (int i = 0; i < 3; ++i) h0[i] = MFMA(w, b1[i], h0[i]);
  w = LD(7);
#pragma unroll
  for (int i = 0; i < 3; ++i) h1[i] = MFMA(w, b1[i], h1[i]);
  w = LD(4);
#pragma unroll
  for (int i = 0; i < 3; ++i) h0[i] = MFMA(w, b2[i], h0[i]);
  w = LD(8);
#pragma unroll
  for (int i = 0; i < 3; ++i) h1[i] = MFMA(w, b2[i], h1[i]);
  w = LD(5);
#pragma unroll
  for (int i = 0; i < 3; ++i) h0[i] = MFMA(w, b3[i], h0[i]);
  w = LD(9);
#pragma unroll
  for (int i = 0; i < 3; ++i) h1[i] = MFMA(w, b3[i], h1[i]);
#pragma unroll
  for (int i = 0; i < 3; ++i) {
    b0[i] = packhalf(h0[i], 0, true); b1[i] = packhalf(h0[i], 8, true);
    b2[i] = packhalf(h1[i], 0, true); b3[i] = packhalf(h1[i], 8, true);
  }

  // sigma = sw2[0,:] . h2 — v_dot2 chain, off the MFMA critical path
  float sg[3] = {0.f, 0.f, 0.f};
#pragma unroll
  for (int q = 0; q < 4; ++q) {
    const u32* pw = (const u32*)(wl + (40 + q) * 512 + lane * 8);
#pragma unroll
    for (int i = 0; i < 3; ++i) {
      union { half8 v; u32 u[4]; } f;
      f.v = (q == 0) ? b0[i] : (q == 1) ? b1[i] : (q == 2) ? b2[i] : b3[i];
#pragma unroll
      for (int k = 0; k < 4; ++k)
        sg[i] = __builtin_amdgcn_fdot2(as_h2(f.u[k]), as_h2(pw[k]), sg[i], false);
    }
  }
#pragma unroll
  for (int i = 0; i < 3; ++i) sg[i] += __shfl_xor(sg[i], 32, 64);

  // color L0' = relu(Wv.views + Wf.h2)  [s2+c0 fused]
  w = LD(18);
#pragma unroll
  for (int i = 0; i < 3; ++i) h0[i] = MFMA(w, bv[i].v, z);
  w = LD(19);
#pragma unroll
  for (int i = 0; i < 3; ++i) h1[i] = MFMA(w, bv[i].v, z);
  w = LD(10);
#pragma unroll
  for (int i = 0; i < 3; ++i) h0[i] = MFMA(w, b0[i], h0[i]);
  w = LD(14);
#pragma unroll
  for (int i = 0; i < 3; ++i) h1[i] = MFMA(w, b0[i], h1[i]);
  w = LD(11);
#pragma unroll
  for (int i = 0; i < 3; ++i) h0[i] = MFMA(w, b1[i], h0[i]);
  w = LD(15);
#pragma unroll
  for (int i = 0; i < 3; ++i) h1[i] = MFMA(w, b1[i], h1[i]);
  w = LD(12);
#pragma unroll
  for (int i = 0; i < 3; ++i) h0[i] = MFMA(w, b2[i], h0[i]);
  w = LD(16);
#pragma unroll
  for (int i = 0; i < 3; ++i) h1[i] = MFMA(w, b2[i], h1[i]);
  w = LD(13);
#pragma unroll
  for (int i = 0; i < 3; ++i) h0[i] = MFMA(w, b3[i], h0[i]);
  w = LD(17);
#pragma unroll
  for (int i = 0; i < 3; ++i) h1[i] = MFMA(w, b3[i], h1[i]);
#pragma unroll
  for (int i = 0; i < 3; ++i) {
    b0[i] = packhalf(h0[i], 0, true); b1[i] = packhalf(h0[i], 8, true);
    b2[i] = packhalf(h1[i], 0, true); b3[i] = packhalf(h1[i], 8, true);
  }

  // color L1
  w = LD(20);
#pragma unroll
  for (int i = 0; i < 3; ++i) h0[i] = MFMA(w, b0[i], z);
  w = LD(24);
#pragma unroll
  for (int i = 0; i < 3; ++i) h1[i] = MFMA(w, b0[i], z);
  w = LD(21);
#pragma unroll
  for (int i = 0; i < 3; ++i) h0[i] = MFMA(w, b1[i], h0[i]);
  w = LD(25);
#pragma unroll
  for (int i = 0; i < 3; ++i) h1[i] = MFMA(w, b1[i], h1[i]);
  w = LD(22);
#pragma unroll
  for (int i = 0; i < 3; ++i) h0[i] = MFMA(w, b2[i], h0[i]);
  w = LD(26);
#pragma unroll
  for (int i = 0; i < 3; ++i) h1[i] = MFMA(w, b2[i], h1[i]);
  w = LD(23);
#pragma unroll
  for (int i = 0; i < 3; ++i) h0[i] = MFMA(w, b3[i], h0[i]);
  w = LD(27);
#pragma unroll
  for (int i = 0; i < 3; ++i) h1[i] = MFMA(w, b3[i], h1[i]);
#pragma unroll
  for (int i = 0; i < 3; ++i) {
    b0[i] = packhalf(h0[i], 0, true); b1[i] = packhalf(h0[i], 8, true);
    b2[i] = packhalf(h1[i], 0, true); b3[i] = packhalf(h1[i], 8, true);
  }

  // color L2
  w = LD(28);
#pragma unroll
  for (int i = 0; i < 3; ++i) h0[i] = MFMA(w, b0[i], z);
  w = LD(32);
#pragma unroll
  for (int i = 0; i < 3; ++i) h1[i] = MFMA(w, b0[i], z);
  w = LD(29);
#pragma unroll
  for (int i = 0; i < 3; ++i) h0[i] = MFMA(w, b1[i], h0[i]);
  w = LD(33);
#pragma unroll
  for (int i = 0; i < 3; ++i) h1[i] = MFMA(w, b1[i], h1[i]);
  w = LD(30);
#pragma unroll
  for (int i = 0; i < 3; ++i) h0[i] = MFMA(w, b2[i], h0[i]);
  w = LD(34);
#pragma unroll
  for (int i = 0; i < 3; ++i) h1[i] = MFMA(w, b2[i], h1[i]);
  w = LD(31);
#pragma unroll
  for (int i = 0; i < 3; ++i) h0[i] = MFMA(w, b3[i], h0[i]);
  w = LD(35);
#pragma unroll
  for (int i = 0; i < 3; ++i) h1[i] = MFMA(w, b3[i], h1[i]);
#pragma unroll
  for (int i = 0; i < 3; ++i) {
    b0[i] = packhalf(h0[i], 0, true); b1[i] = packhalf(h0[i], 8, true);
    b2[i] = packhalf(h1[i], 0, true); b3[i] = packhalf(h1[i], 8, true);
  }

  // color L3 (64->3, NO relu) — reuse h0 as the output acc
  w = LD(36);
#pragma unroll
  for (int i = 0; i < 3; ++i) h0[i] = MFMA(w, b0[i], z);
  w = LD(37);
#pragma unroll
  for (int i = 0; i < 3; ++i) h0[i] = MFMA(w, b1[i], h0[i]);
  w = LD(38);
#pragma unroll
  for (int i = 0; i < 3; ++i) h0[i] = MFMA(w, b2[i], h0[i]);
  w = LD(39);
#pragma unroll
  for (int i = 0; i < 3; ++i) h0[i] = MFMA(w, b3[i], h0[i]);

#pragma unroll
  for (int i = 0; i < 3; ++i) {
    if (lane < 32 && ok[i]) {
      float4 o;
      o.x = h0[i][0]; o.y = h0[i][1]; o.z = h0[i][2]; o.w = sg[i];
      *(float4*)(out + (size_t)pt[i] * 4) = o;
    }
  }
#undef LD
}

extern "C" void kernel_launch(void* const* d_in, const int* in_sizes, int n_in,
                              void* d_out, int out_size, void* d_ws, size_t ws_size,
                              hipStream_t stream) {
  const float* x = (const float*)d_in[0];
  const float* sw0 = (const float*)d_in[1];
  const float* sw1 = (const float*)d_in[2];
  const float* sw2 = (const float*)d_in[3];
  const float* cw0 = (const float*)d_in[4];
  const float* cw1 = (const float*)d_in[5];
  const float* cw2 = (const float*)d_in[6];
  const float* cw3 = (const float*)d_in[7];
  float* out = (float*)d_out;
  uint4* pool = (uint4*)d_ws;  // 45056 B used

  const int npts = in_sizes[0] / 6;         // 1048576
  const int ntiles = npts >> 5;             // 32768
  const int blocks = (ntiles + 11) / 12;    // 2731 (4 waves x 3 tiles each)

  build_pool<<<NFRAG, 64, 0, stream>>>(sw0, sw1, sw2, cw0, cw1, cw2, cw3, pool);
  nerf_fused<<<blocks, 256, 0, stream>>>(x, pool, out, npts);
}